// Round 1
// baseline (678.475 us; speedup 1.0000x reference)
//
#include <hip/hip_runtime.h>
#include <hip/hip_bf16.h>
#include <math.h>

#define BATCH 1024

// ---------------- row squared-norm: xsq[b] = sum_i x[b,i]^2 ----------------
__global__ __launch_bounds__(256) void rowsq_kernel(const float* __restrict__ x,
                                                    float* __restrict__ xsq, int cols) {
    int row = blockIdx.x;
    const float* xr = x + (size_t)row * cols;
    float s = 0.f;
    for (int i = threadIdx.x; i < cols; i += 256) {
        float v = xr[i];
        s += v * v;
    }
    // wave64 reduce
    #pragma unroll
    for (int off = 32; off; off >>= 1) s += __shfl_down(s, off, 64);
    __shared__ float lds[4];
    int lane = threadIdx.x & 63, wid = threadIdx.x >> 6;
    if (lane == 0) lds[wid] = s;
    __syncthreads();
    if (threadIdx.x == 0) xsq[row] = lds[0] + lds[1] + lds[2] + lds[3];
}

// ---------------- col squared-norm: wsq[j] = sum_i w[i,j]^2 ----------------
__global__ __launch_bounds__(256) void colsq_kernel(const float* __restrict__ w,
                                                    float* __restrict__ wsq,
                                                    int rows, int cols) {
    int j = blockIdx.x * 256 + threadIdx.x;
    if (j >= cols) return;
    float s = 0.f;
    for (int i = 0; i < rows; ++i) {
        float v = w[(size_t)i * cols + j];
        s += v * v;
    }
    wsq[j] = s;
}

// ---------------- GEMM with euclid epilogue ----------------
// Z[b,j] = (x @ w)[b,j] - 0.5*(xsq[b] + wsq[j])   == -0.5*||x_b - w_:,j||^2
#define BM 64
#define BN 64
#define KT 16
__global__ __launch_bounds__(256) void gemm_euclid_kernel(
    const float* __restrict__ A, const float* __restrict__ Bw,
    const float* __restrict__ xsq, const float* __restrict__ wsq,
    float* __restrict__ Z, int M, int K, int N) {
    __shared__ float As[KT][BM + 1];
    __shared__ float Bs[KT][BN];
    const int tid = threadIdx.x;
    const int tx = tid & 15, ty = tid >> 4;
    const int row0 = blockIdx.y * BM, col0 = blockIdx.x * BN;

    float acc[4][4] = {};

    for (int k0 = 0; k0 < K; k0 += KT) {
        // A tile: As[k][m] = A[(row0+m)*K + k0+k]; tid-fastest over k -> coalesced 16-float runs
        #pragma unroll
        for (int l = 0; l < 4; ++l) {
            int idx = tid + l * 256;
            int k = idx & 15, m = idx >> 4;
            int gr = row0 + m, gk = k0 + k;
            As[k][m] = (gr < M && gk < K) ? A[(size_t)gr * K + gk] : 0.f;
        }
        // B tile: Bs[k][n] = Bw[(k0+k)*N + col0+n]; tid-fastest over n -> coalesced
        #pragma unroll
        for (int l = 0; l < 4; ++l) {
            int idx = tid + l * 256;
            int n = idx & 63, k = idx >> 6;
            int gk = k0 + k, gc = col0 + n;
            Bs[k][n] = (gk < K && gc < N) ? Bw[(size_t)gk * N + gc] : 0.f;
        }
        __syncthreads();

        #pragma unroll
        for (int k = 0; k < KT; ++k) {
            float a[4], b[4];
            #pragma unroll
            for (int i = 0; i < 4; ++i) a[i] = As[k][ty + i * 16];
            #pragma unroll
            for (int j = 0; j < 4; ++j) b[j] = Bs[k][tx + j * 16];
            #pragma unroll
            for (int i = 0; i < 4; ++i)
                #pragma unroll
                for (int j = 0; j < 4; ++j) acc[i][j] += a[i] * b[j];
        }
        __syncthreads();
    }

    #pragma unroll
    for (int i = 0; i < 4; ++i) {
        int r = row0 + ty + i * 16;
        if (r >= M) continue;
        float xs = xsq[r];
        #pragma unroll
        for (int j = 0; j < 4; ++j) {
            int c = col0 + tx + j * 16;
            if (c < N) Z[(size_t)r * N + c] = acc[i][j] - 0.5f * (xs + wsq[c]);
        }
    }
}

// ---------------- fused BatchNorm(train) + activation ----------------
// One block per column j. 256 threads x 4 rows each = 1024 rows in registers.
// ACT: 0 = relu, 1 = sigmoid
template <int ACT>
__global__ __launch_bounds__(256) void bnact_kernel(const float* __restrict__ z,
                                                    const float* __restrict__ gamma,
                                                    const float* __restrict__ beta,
                                                    float* __restrict__ h, int N) {
    const int j = blockIdx.x;
    const int tid = threadIdx.x;
    __shared__ float lds[4];

    float v[4];
    #pragma unroll
    for (int k = 0; k < 4; ++k) v[k] = z[(size_t)(tid + k * 256) * N + j];

    // pass 1: mean
    float s = v[0] + v[1] + v[2] + v[3];
    #pragma unroll
    for (int off = 32; off; off >>= 1) s += __shfl_down(s, off, 64);
    int lane = tid & 63, wid = tid >> 6;
    if (lane == 0) lds[wid] = s;
    __syncthreads();
    float mean = (lds[0] + lds[1] + lds[2] + lds[3]) * (1.f / BATCH);
    __syncthreads();

    // pass 2: variance around mean (numerically stable; values live in regs)
    float ss = 0.f;
    #pragma unroll
    for (int k = 0; k < 4; ++k) {
        float d = v[k] - mean;
        ss += d * d;
    }
    #pragma unroll
    for (int off = 32; off; off >>= 1) ss += __shfl_down(ss, off, 64);
    if (lane == 0) lds[wid] = ss;
    __syncthreads();
    float var = (lds[0] + lds[1] + lds[2] + lds[3]) * (1.f / BATCH);

    float inv = 1.f / sqrtf(var + 1e-5f);
    float g = gamma[j], bb = beta[j];
    #pragma unroll
    for (int k = 0; k < 4; ++k) {
        float y = g * (v[k] - mean) * inv + bb;
        if (ACT == 0) {
            y = y > 0.f ? y : 0.f;
        } else {
            y = 1.f / (1.f + expf(-y));
        }
        h[(size_t)(tid + k * 256) * N + j] = y;
    }
}

extern "C" void kernel_launch(void* const* d_in, const int* in_sizes, int n_in,
                              void* d_out, int out_size, void* d_ws, size_t ws_size,
                              hipStream_t stream) {
    const float* X  = (const float*)d_in[0];
    const float* W1 = (const float*)d_in[1];
    const float* g1 = (const float*)d_in[2];
    const float* b1 = (const float*)d_in[3];
    const float* W2 = (const float*)d_in[4];
    const float* g2 = (const float*)d_in[5];
    const float* b2 = (const float*)d_in[6];
    const float* W3 = (const float*)d_in[7];
    const float* g3 = (const float*)d_in[8];
    const float* b3 = (const float*)d_in[9];
    const float* W4 = (const float*)d_in[10];
    const float* g4 = (const float*)d_in[11];
    const float* b4 = (const float*)d_in[12];

    float* ws  = (float*)d_ws;
    float* z   = ws;                  // 1024*784
    float* h1  = z   + 1024 * 784;    // 1024*392
    float* h2  = h1  + 1024 * 392;    // 1024*8
    float* h3  = h2  + 1024 * 8;      // 1024*392
    float* xsq = h3  + 1024 * 392;    // 1024
    float* wsq = xsq + 1024;          // 784

    float* outp = (float*)d_out;

    // ---- Layer 1: X[1024,784] x W1[784,392] -> h1 ----
    rowsq_kernel<<<BATCH, 256, 0, stream>>>(X, xsq, 784);
    colsq_kernel<<<(392 + 255) / 256, 256, 0, stream>>>(W1, wsq, 784, 392);
    {
        dim3 grid((392 + BN - 1) / BN, BATCH / BM);
        gemm_euclid_kernel<<<grid, 256, 0, stream>>>(X, W1, xsq, wsq, z, BATCH, 784, 392);
    }
    bnact_kernel<0><<<392, 256, 0, stream>>>(z, g1, b1, h1, 392);

    // ---- Layer 2: h1[1024,392] x W2[392,8] -> h2 ----
    rowsq_kernel<<<BATCH, 256, 0, stream>>>(h1, xsq, 392);
    colsq_kernel<<<1, 256, 0, stream>>>(W2, wsq, 392, 8);
    {
        dim3 grid(1, BATCH / BM);
        gemm_euclid_kernel<<<grid, 256, 0, stream>>>(h1, W2, xsq, wsq, z, BATCH, 392, 8);
    }
    bnact_kernel<0><<<8, 256, 0, stream>>>(z, g2, b2, h2, 8);

    // ---- Layer 3: h2[1024,8] x W3[8,392] -> h3 ----
    rowsq_kernel<<<BATCH, 256, 0, stream>>>(h2, xsq, 8);
    colsq_kernel<<<(392 + 255) / 256, 256, 0, stream>>>(W3, wsq, 8, 392);
    {
        dim3 grid((392 + BN - 1) / BN, BATCH / BM);
        gemm_euclid_kernel<<<grid, 256, 0, stream>>>(h2, W3, xsq, wsq, z, BATCH, 8, 392);
    }
    bnact_kernel<0><<<392, 256, 0, stream>>>(z, g3, b3, h3, 392);

    // ---- Layer 4: h3[1024,392] x W4[392,784] -> out (sigmoid) ----
    rowsq_kernel<<<BATCH, 256, 0, stream>>>(h3, xsq, 392);
    colsq_kernel<<<(784 + 255) / 256, 256, 0, stream>>>(W4, wsq, 392, 784);
    {
        dim3 grid((784 + BN - 1) / BN, BATCH / BM);
        gemm_euclid_kernel<<<grid, 256, 0, stream>>>(h3, W4, xsq, wsq, z, BATCH, 392, 784);
    }
    bnact_kernel<1><<<784, 256, 0, stream>>>(z, g4, b4, outp, 784);
}

// Round 2
// 352.366 us; speedup vs baseline: 1.9255x; 1.9255x over previous
//
#include <hip/hip_runtime.h>
#include <hip/hip_bf16.h>
#include <math.h>

#define BATCH 1024

// ---------------- GEMM with fused euclid norms + epilogue ----------------
// Z[b,j] = (x @ w)[b,j] - 0.5*(xsq[b] + wsq[j])   == -0.5*||x_b - w_:,j||^2
// xsq and wsq are computed INSIDE the kernel from the same LDS-staged tiles:
// each block traverses the full K extent for its 64 rows and 64 cols, so
// per-thread partial sums of squares cover all of K with a cheap reduction.
#define BM 64
#define BN 64
#define KT 16
__global__ __launch_bounds__(256) void gemm_euclid_kernel(
    const float* __restrict__ A, const float* __restrict__ Bw,
    float* __restrict__ Z, int M, int K, int N) {
    __shared__ float As[KT][BM + 1];
    __shared__ float Bs[KT][BN];
    __shared__ float bred[4][BN];
    __shared__ float xsq_s[BM];
    __shared__ float wsq_s[BN];

    const int tid = threadIdx.x;
    const int tx = tid & 15, ty = tid >> 4;
    const int row0 = blockIdx.y * BM, col0 = blockIdx.x * BN;

    float acc[4][4] = {};
    float asq[4] = {};   // A-row partials: rows m = (tid>>4) + 16*l, k-slice k≡tid&15 (mod16)
    float bsq = 0.f;     // B-col partial: col n = tid&63, k-slice k≡tid>>6 (mod 4)

    for (int k0 = 0; k0 < K; k0 += KT) {
        // A tile: As[k][m] = A[(row0+m)*K + k0+k]
        // idx = tid + l*256 -> k = tid&15 (const per thread), m = (tid>>4) + 16*l
        #pragma unroll
        for (int l = 0; l < 4; ++l) {
            int m = (tid >> 4) + 16 * l;
            int k = tid & 15;
            int gr = row0 + m, gk = k0 + k;
            float v = (gr < M && gk < K) ? A[(size_t)gr * K + gk] : 0.f;
            As[k][m] = v;
            asq[l] += v * v;
        }
        // B tile: Bs[k][n] = Bw[(k0+k)*N + col0+n]
        // idx = tid + l*256 -> n = tid&63 (const per thread), k = (tid>>6) + 4*l
        #pragma unroll
        for (int l = 0; l < 4; ++l) {
            int n = tid & 63;
            int k = (tid >> 6) + 4 * l;
            int gk = k0 + k, gc = col0 + n;
            float v = (gk < K && gc < N) ? Bw[(size_t)gk * N + gc] : 0.f;
            Bs[k][n] = v;
            bsq += v * v;
        }
        __syncthreads();

        #pragma unroll
        for (int k = 0; k < KT; ++k) {
            float a[4], b[4];
            #pragma unroll
            for (int i = 0; i < 4; ++i) a[i] = As[k][ty + i * 16];
            #pragma unroll
            for (int j = 0; j < 4; ++j) b[j] = Bs[k][tx + j * 16];
            #pragma unroll
            for (int i = 0; i < 4; ++i)
                #pragma unroll
                for (int j = 0; j < 4; ++j) acc[i][j] += a[i] * b[j];
        }
        __syncthreads();
    }

    // ---- reduce xsq: sum over the 16 lanes tid&15 = 0..15 (same tid>>4 group) ----
    #pragma unroll
    for (int l = 0; l < 4; ++l) {
        float s = asq[l];
        #pragma unroll
        for (int msk = 1; msk < 16; msk <<= 1) s += __shfl_xor(s, msk, 64);
        if ((tid & 15) == 0) xsq_s[(tid >> 4) + 16 * l] = s;
    }
    // ---- reduce wsq: fold the 4 k-slices (threads tid, tid+64, tid+128, tid+192) ----
    bred[tid >> 6][tid & 63] = bsq;
    __syncthreads();
    if (tid < BN) wsq_s[tid] = bred[0][tid] + bred[1][tid] + bred[2][tid] + bred[3][tid];
    __syncthreads();

    #pragma unroll
    for (int i = 0; i < 4; ++i) {
        int r = row0 + ty + i * 16;
        if (r >= M) continue;
        float xs = xsq_s[ty + i * 16];
        #pragma unroll
        for (int j = 0; j < 4; ++j) {
            int c = col0 + tx + j * 16;
            if (c < N) Z[(size_t)r * N + c] = acc[i][j] - 0.5f * (xs + wsq_s[tx + j * 16]);
        }
    }
}

// ---------------- fused BatchNorm(train) + activation ----------------
// One block per column j. 256 threads x 4 rows each = 1024 rows in registers.
// ACT: 0 = relu, 1 = sigmoid
template <int ACT>
__global__ __launch_bounds__(256) void bnact_kernel(const float* __restrict__ z,
                                                    const float* __restrict__ gamma,
                                                    const float* __restrict__ beta,
                                                    float* __restrict__ h, int N) {
    const int j = blockIdx.x;
    const int tid = threadIdx.x;
    __shared__ float lds[4];

    float v[4];
    #pragma unroll
    for (int k = 0; k < 4; ++k) v[k] = z[(size_t)(tid + k * 256) * N + j];

    // pass 1: mean
    float s = v[0] + v[1] + v[2] + v[3];
    #pragma unroll
    for (int off = 32; off; off >>= 1) s += __shfl_down(s, off, 64);
    int lane = tid & 63, wid = tid >> 6;
    if (lane == 0) lds[wid] = s;
    __syncthreads();
    float mean = (lds[0] + lds[1] + lds[2] + lds[3]) * (1.f / BATCH);
    __syncthreads();

    // pass 2: variance around mean (numerically stable; values live in regs)
    float ss = 0.f;
    #pragma unroll
    for (int k = 0; k < 4; ++k) {
        float d = v[k] - mean;
        ss += d * d;
    }
    #pragma unroll
    for (int off = 32; off; off >>= 1) ss += __shfl_down(ss, off, 64);
    if (lane == 0) lds[wid] = ss;
    __syncthreads();
    float var = (lds[0] + lds[1] + lds[2] + lds[3]) * (1.f / BATCH);

    float inv = 1.f / sqrtf(var + 1e-5f);
    float g = gamma[j], bb = beta[j];
    #pragma unroll
    for (int k = 0; k < 4; ++k) {
        float y = g * (v[k] - mean) * inv + bb;
        if (ACT == 0) {
            y = y > 0.f ? y : 0.f;
        } else {
            y = 1.f / (1.f + expf(-y));
        }
        h[(size_t)(tid + k * 256) * N + j] = y;
    }
}

extern "C" void kernel_launch(void* const* d_in, const int* in_sizes, int n_in,
                              void* d_out, int out_size, void* d_ws, size_t ws_size,
                              hipStream_t stream) {
    const float* X  = (const float*)d_in[0];
    const float* W1 = (const float*)d_in[1];
    const float* g1 = (const float*)d_in[2];
    const float* b1 = (const float*)d_in[3];
    const float* W2 = (const float*)d_in[4];
    const float* g2 = (const float*)d_in[5];
    const float* b2 = (const float*)d_in[6];
    const float* W3 = (const float*)d_in[7];
    const float* g3 = (const float*)d_in[8];
    const float* b3 = (const float*)d_in[9];
    const float* W4 = (const float*)d_in[10];
    const float* g4 = (const float*)d_in[11];
    const float* b4 = (const float*)d_in[12];

    float* ws  = (float*)d_ws;
    float* z   = ws;                  // 1024*784
    float* h1  = z   + 1024 * 784;    // 1024*392
    float* h2  = h1  + 1024 * 392;    // 1024*8
    float* h3  = h2  + 1024 * 8;      // 1024*392

    float* outp = (float*)d_out;

    // ---- Layer 1: X[1024,784] x W1[784,392] -> h1 ----
    {
        dim3 grid((392 + BN - 1) / BN, BATCH / BM);
        gemm_euclid_kernel<<<grid, 256, 0, stream>>>(X, W1, z, BATCH, 784, 392);
    }
    bnact_kernel<0><<<392, 256, 0, stream>>>(z, g1, b1, h1, 392);

    // ---- Layer 2: h1[1024,392] x W2[392,8] -> h2 ----
    {
        dim3 grid(1, BATCH / BM);
        gemm_euclid_kernel<<<grid, 256, 0, stream>>>(h1, W2, z, BATCH, 392, 8);
    }
    bnact_kernel<0><<<8, 256, 0, stream>>>(z, g2, b2, h2, 8);

    // ---- Layer 3: h2[1024,8] x W3[8,392] -> h3 ----
    {
        dim3 grid((392 + BN - 1) / BN, BATCH / BM);
        gemm_euclid_kernel<<<grid, 256, 0, stream>>>(h2, W3, z, BATCH, 8, 392);
    }
    bnact_kernel<0><<<392, 256, 0, stream>>>(z, g3, b3, h3, 392);

    // ---- Layer 4: h3[1024,392] x W4[392,784] -> out (sigmoid) ----
    {
        dim3 grid((784 + BN - 1) / BN, BATCH / BM);
        gemm_euclid_kernel<<<grid, 256, 0, stream>>>(h3, W4, z, BATCH, 392, 784);
    }
    bnact_kernel<1><<<784, 256, 0, stream>>>(z, g4, b4, outp, 784);
}

// Round 3
// 105.888 us; speedup vs baseline: 6.4075x; 3.3277x over previous
//
#include <hip/hip_runtime.h>
#include <hip/hip_bf16.h>
#include <math.h>

#define BATCH 1024
#define BM 64
#define BN 64
#define BK 32
#define LDK 40   // padded LDS row stride (bf16 units): 80 B = 16B-aligned frags, 2-way max conflicts

typedef __attribute__((ext_vector_type(8))) short bf16x8;
typedef __attribute__((ext_vector_type(4))) float f32x4;

static __device__ __forceinline__ ushort f2bf(float f) {
    union { float f; unsigned u; } v; v.f = f;
    unsigned r = (v.u + 0x7fffu + ((v.u >> 16) & 1u)) >> 16;  // RNE
    return (ushort)r;
}

// ---------------- bf16-MFMA GEMM with fused euclid norms + epilogue ----------------
// Z[b,j] = (x @ w)[b,j] - 0.5*(xsq[b] + wsq[j]); dot in bf16 MFMA (fp32 accum),
// norms in fp32 from the pre-conversion staged values.
__global__ __launch_bounds__(256) void gemm_euclid_mfma(
    const float* __restrict__ A, const float* __restrict__ Bw,
    float* __restrict__ Z, int M, int K, int N)
{
    __shared__ ushort As[2][BM][LDK];   // As[buf][row][k] = bf16(A[row0+row][kbase+k])
    __shared__ ushort Bs[2][BN][LDK];   // Bs[buf][col][k] = bf16(B[kbase+k][col0+col]) (transposed)
    __shared__ float bred[4][BN];
    __shared__ float xsq_s[BM];
    __shared__ float wsq_s[BN];

    const int tid = threadIdx.x;
    const int lane = tid & 63;
    const int wv = tid >> 6;
    const int wr = wv >> 1, wc = wv & 1;          // 2x2 wave grid, each wave 32x32 out
    const int row0 = blockIdx.y * BM, col0 = blockIdx.x * BN;

    // staging coords: A: row ar(+32), k = ak..ak+3 (float4); B: col bn, k = bk+4i
    const int ar = tid >> 3;          // 0..31
    const int ak = (tid & 7) * 4;     // 0..28
    const int bn = tid & 63;
    const int bk = tid >> 6;          // 0..3

    const int fr = lane & 15;         // fragment row/col within 16
    const int fg = lane >> 4;         // k-group (8 bf16 each)

    f32x4 acc[2][2] = {};
    float asq[2] = {0.f, 0.f};
    float bsq = 0.f;
    float areg[2][4];
    float breg[8];

    const int ntiles = (K + BK - 1) / BK;

    auto load_tile = [&](int t) {
        const int kbase = t * BK;
        if (kbase + BK <= K) {
            #pragma unroll
            for (int l = 0; l < 2; ++l) {
                const float* p = A + (size_t)(row0 + ar + 32 * l) * K + kbase + ak;
                f32x4 v = *(const f32x4*)p;
                #pragma unroll
                for (int j = 0; j < 4; ++j) areg[l][j] = v[j];
            }
            const int gc = col0 + bn;
            #pragma unroll
            for (int i = 0; i < 8; ++i)
                breg[i] = (gc < N) ? Bw[(size_t)(kbase + bk + 4 * i) * N + gc] : 0.f;
        } else {
            #pragma unroll
            for (int l = 0; l < 2; ++l)
                #pragma unroll
                for (int j = 0; j < 4; ++j) {
                    int gk = kbase + ak + j;
                    areg[l][j] = (gk < K) ? A[(size_t)(row0 + ar + 32 * l) * K + gk] : 0.f;
                }
            const int gc = col0 + bn;
            #pragma unroll
            for (int i = 0; i < 8; ++i) {
                int gk = kbase + bk + 4 * i;
                breg[i] = (gk < K && gc < N) ? Bw[(size_t)gk * N + gc] : 0.f;
            }
        }
    };

    auto store_tile = [&](int buf) {
        #pragma unroll
        for (int l = 0; l < 2; ++l) {
            ushort4 h;
            h.x = f2bf(areg[l][0]); h.y = f2bf(areg[l][1]);
            h.z = f2bf(areg[l][2]); h.w = f2bf(areg[l][3]);
            asq[l] += areg[l][0]*areg[l][0] + areg[l][1]*areg[l][1]
                    + areg[l][2]*areg[l][2] + areg[l][3]*areg[l][3];
            *(ushort4*)&As[buf][ar + 32 * l][ak] = h;   // 8B-aligned ds_write_b64
        }
        #pragma unroll
        for (int i = 0; i < 8; ++i) {
            bsq += breg[i] * breg[i];
            Bs[buf][bn][bk + 4 * i] = f2bf(breg[i]);
        }
    };

    auto compute = [&](int buf) {
        bf16x8 af[2], bfr[2];
        #pragma unroll
        for (int m = 0; m < 2; ++m)
            af[m] = *(const bf16x8*)&As[buf][wr * 32 + m * 16 + fr][fg * 8];
        #pragma unroll
        for (int n = 0; n < 2; ++n)
            bfr[n] = *(const bf16x8*)&Bs[buf][wc * 32 + n * 16 + fr][fg * 8];
        #pragma unroll
        for (int m = 0; m < 2; ++m)
            #pragma unroll
            for (int n = 0; n < 2; ++n)
                acc[m][n] = __builtin_amdgcn_mfma_f32_16x16x32_bf16(af[m], bfr[n], acc[m][n], 0, 0, 0);
    };

    load_tile(0);
    store_tile(0);
    __syncthreads();
    for (int t = 0; t < ntiles; ++t) {
        if (t + 1 < ntiles) load_tile(t + 1);       // global -> regs (next tile)
        compute(t & 1);                              // ds_read + mfma (current)
        if (t + 1 < ntiles) store_tile((t + 1) & 1); // regs -> other LDS buf
        __syncthreads();
    }

    // ---- xsq: reduce over the 8 threads sharing a row (masks 1,2,4 within wave) ----
    #pragma unroll
    for (int l = 0; l < 2; ++l) {
        float s = asq[l];
        s += __shfl_xor(s, 1, 64);
        s += __shfl_xor(s, 2, 64);
        s += __shfl_xor(s, 4, 64);
        if ((tid & 7) == 0) xsq_s[ar + 32 * l] = s;
    }
    // ---- wsq: fold 4 k-slices ----
    bred[bk][bn] = bsq;
    __syncthreads();
    if (tid < BN) wsq_s[tid] = bred[0][tid] + bred[1][tid] + bred[2][tid] + bred[3][tid];
    __syncthreads();

    // ---- epilogue: C/D layout col=lane&15, row=(lane>>4)*4+reg (m89-verified) ----
    #pragma unroll
    for (int n = 0; n < 2; ++n) {
        int c = col0 + wc * 32 + n * 16 + fr;
        if (c >= N) continue;
        float wsq = wsq_s[wc * 32 + n * 16 + fr];
        #pragma unroll
        for (int m = 0; m < 2; ++m) {
            #pragma unroll
            for (int j = 0; j < 4; ++j) {
                int rl = wr * 32 + m * 16 + fg * 4 + j;
                int r = row0 + rl;
                if (r < M) Z[(size_t)r * N + c] = acc[m][n][j] - 0.5f * (xsq_s[rl] + wsq);
            }
        }
    }
}

// ---------------- fused BatchNorm(train) + activation ----------------
template <int ACT>
__global__ __launch_bounds__(256) void bnact_kernel(const float* __restrict__ z,
                                                    const float* __restrict__ gamma,
                                                    const float* __restrict__ beta,
                                                    float* __restrict__ h, int N) {
    const int j = blockIdx.x;
    const int tid = threadIdx.x;
    __shared__ float lds[4];

    float v[4];
    #pragma unroll
    for (int k = 0; k < 4; ++k) v[k] = z[(size_t)(tid + k * 256) * N + j];

    float s = v[0] + v[1] + v[2] + v[3];
    #pragma unroll
    for (int off = 32; off; off >>= 1) s += __shfl_down(s, off, 64);
    int lane = tid & 63, wid = tid >> 6;
    if (lane == 0) lds[wid] = s;
    __syncthreads();
    float mean = (lds[0] + lds[1] + lds[2] + lds[3]) * (1.f / BATCH);
    __syncthreads();

    float ss = 0.f;
    #pragma unroll
    for (int k = 0; k < 4; ++k) {
        float d = v[k] - mean;
        ss += d * d;
    }
    #pragma unroll
    for (int off = 32; off; off >>= 1) ss += __shfl_down(ss, off, 64);
    if (lane == 0) lds[wid] = ss;
    __syncthreads();
    float var = (lds[0] + lds[1] + lds[2] + lds[3]) * (1.f / BATCH);

    float inv = 1.f / sqrtf(var + 1e-5f);
    float g = gamma[j], bb = beta[j];
    #pragma unroll
    for (int k = 0; k < 4; ++k) {
        float y = g * (v[k] - mean) * inv + bb;
        if (ACT == 0) {
            y = y > 0.f ? y : 0.f;
        } else {
            y = 1.f / (1.f + expf(-y));
        }
        h[(size_t)(tid + k * 256) * N + j] = y;
    }
}

extern "C" void kernel_launch(void* const* d_in, const int* in_sizes, int n_in,
                              void* d_out, int out_size, void* d_ws, size_t ws_size,
                              hipStream_t stream) {
    const float* X  = (const float*)d_in[0];
    const float* W1 = (const float*)d_in[1];
    const float* g1 = (const float*)d_in[2];
    const float* b1 = (const float*)d_in[3];
    const float* W2 = (const float*)d_in[4];
    const float* g2 = (const float*)d_in[5];
    const float* b2 = (const float*)d_in[6];
    const float* W3 = (const float*)d_in[7];
    const float* g3 = (const float*)d_in[8];
    const float* b3 = (const float*)d_in[9];
    const float* W4 = (const float*)d_in[10];
    const float* g4 = (const float*)d_in[11];
    const float* b4 = (const float*)d_in[12];

    float* ws  = (float*)d_ws;
    float* z   = ws;                  // 1024*784
    float* h1  = z   + 1024 * 784;    // 1024*392
    float* h2  = h1  + 1024 * 392;    // 1024*8
    float* h3  = h2  + 1024 * 8;      // 1024*392

    float* outp = (float*)d_out;

    // ---- Layer 1: X[1024,784] x W1[784,392] -> h1 ----
    gemm_euclid_mfma<<<dim3(7, 16), 256, 0, stream>>>(X, W1, z, BATCH, 784, 392);
    bnact_kernel<0><<<392, 256, 0, stream>>>(z, g1, b1, h1, 392);

    // ---- Layer 2: h1[1024,392] x W2[392,8] -> h2 ----
    gemm_euclid_mfma<<<dim3(1, 16), 256, 0, stream>>>(h1, W2, z, BATCH, 392, 8);
    bnact_kernel<0><<<8, 256, 0, stream>>>(z, g2, b2, h2, 8);

    // ---- Layer 3: h2[1024,8] x W3[8,392] -> h3 ----
    gemm_euclid_mfma<<<dim3(7, 16), 256, 0, stream>>>(h2, W3, z, BATCH, 8, 392);
    bnact_kernel<0><<<392, 256, 0, stream>>>(z, g3, b3, h3, 392);

    // ---- Layer 4: h3[1024,392] x W4[392,784] -> out (sigmoid) ----
    gemm_euclid_mfma<<<dim3(13, 16), 256, 0, stream>>>(h3, W4, z, BATCH, 392, 784);
    bnact_kernel<1><<<784, 256, 0, stream>>>(z, g4, b4, outp, 784);
}